// Round 5
// baseline (355.346 us; speedup 1.0000x reference)
//
#include <hip/hip_runtime.h>
#include <cstdint>
#include <cstddef>

// Problem: B=128, S=512, H=512
//   context[b,h] = sum_s softmax_s( sum_k tanh(u[b,s,k]) Ve[k] ) * h[b,s,h]
//   u = h@U1a^T + x@U2^T + (h_last@U1b^T broadcast over s)
// R5: 32x32x16 MFMA (LDS-read:MFMA ratio 1.0), single 32KB LDS buffer,
//   reg-staged A+B with write-late cvt, lgkm-only barriers (loads cross
//   barriers in registers), 12 waves/CU. BM=128 BN=128 BK=64, 4 waves 2x2,
//   wave tile 64x64 (2x2 frags of 32x32, 64-AGPR acc).

typedef _Float16 h8     __attribute__((ext_vector_type(8)));
typedef float    f4     __attribute__((ext_vector_type(4)));
typedef float    f32x16 __attribute__((ext_vector_type(16)));

// lgkm-only barrier: publish LDS writes / retire LDS reads, do NOT drain vmcnt
// (in-flight register global-loads stay outstanding across the barrier).
#define LBAR()                                                                 \
  do {                                                                         \
    asm volatile("s_waitcnt lgkmcnt(0)\n\ts_barrier" ::: "memory");            \
    __builtin_amdgcn_sched_barrier(0);                                         \
  } while (0)

// ---------------------------------------------------------------------------
// Setup: Bws[kt][n][64] fp16, kt-contiguous (each K-tile = 64KB linear).
// Bws[kt*32768 + n*64 + k] = fp16( U[n][kt*64+k] ),
// U[n][k] = k<512 ? U1[n][k] : U2[n][k-512]
// ---------------------------------------------------------------------------
__global__ void bsetup_kernel(const float* __restrict__ U1, const float* __restrict__ U2,
                              _Float16* __restrict__ Bws) {
  int g = blockIdx.x * 256 + threadIdx.x;   // 65536 slots of 8 fp16
  int j  = g & 7;
  int n  = (g >> 3) & 511;
  int kt = g >> 12;
  int k0 = kt * 64 + j * 8;
  const float* p = (k0 < 512) ? (U1 + (size_t)n * 1024 + k0)
                              : (U2 + (size_t)n * 512 + (k0 - 512));
  float4 a = *(const float4*)p;
  float4 b = *(const float4*)(p + 4);
  _Float16 hv[8];
  hv[0]=(_Float16)a.x; hv[1]=(_Float16)a.y; hv[2]=(_Float16)a.z; hv[3]=(_Float16)a.w;
  hv[4]=(_Float16)b.x; hv[5]=(_Float16)b.y; hv[6]=(_Float16)b.z; hv[7]=(_Float16)b.w;
  *(uint4*)(Bws + (size_t)kt * 32768 + n * 64 + j * 8) = *(uint4*)hv;
}

// ---------------------------------------------------------------------------
// bias[b][n] = sum_h h[b][S-1][h] * U1[n][512+h]   (fp32, exact)
// ---------------------------------------------------------------------------
__global__ void bias_kernel(const float* __restrict__ hT, const float* __restrict__ U1,
                            float* __restrict__ bias) {
  const int b = blockIdx.x, t = threadIdx.x;
  const int l = t & 63, w = t >> 6;
  __shared__ float4 hl[128];
  if (t < 128) hl[t] = *(const float4*)(hT + ((size_t)b * 512 + 511) * 512 + t * 4);
  __syncthreads();
  for (int n = w; n < 512; n += 4) {
    const float4* ur = (const float4*)(U1 + (size_t)n * 1024 + 512);
    float4 u0 = ur[l],      u1 = ur[l + 64];
    float4 h0 = hl[l],      h1 = hl[l + 64];
    float s = u0.x*h0.x + u0.y*h0.y + u0.z*h0.z + u0.w*h0.w
            + u1.x*h1.x + u1.y*h1.y + u1.z*h1.z + u1.w*h1.w;
#pragma unroll
    for (int d = 1; d < 64; d <<= 1) s += __shfl_xor(s, d, 64);
    if (l == 0) bias[(size_t)b * 512 + n] = s;
  }
}

// ---------------------------------------------------------------------------
// Fused GEMM: M=65536, N=512 (4 N-tiles of 128), K=1024, BK=64.
// ---------------------------------------------------------------------------
__global__ __launch_bounds__(256, 3)
void gemm_kernel(const float* __restrict__ hT, const float* __restrict__ xT,
                 const _Float16* __restrict__ Bws, const float* __restrict__ bias,
                 const float* __restrict__ Ve, float* __restrict__ e) {
  // XCD-chunked swizzle: the 4 nt-siblings of one bm land consecutively on
  // one XCD -> A-panel L2 reuse; bm-range partitioned across XCDs.
  const int bid  = ((int)blockIdx.x & 7) * 256 + ((int)blockIdx.x >> 3);
  const int bm   = bid >> 2;
  const int nt   = bid & 3;
  const int row0 = bm * 128;
  const int bb   = row0 >> 9;
  const int t    = threadIdx.x;
  const int l    = t & 63;
  const int wv   = t >> 6;
  const int wm   = wv >> 1, wn = wv & 1;
  const int l31  = l & 31, khalf = l >> 5;

  __shared__ __align__(16) _Float16 Asm[128 * 64];   // 16 KB, rows 128 B
  __shared__ __align__(16) _Float16 Bsm[128 * 64];   // 16 KB, rows 128 B

  f4    areg[8];   // A stage: 32 f32 per thread
  uint4 breg[4];   // B stage: 64 B fp16 per thread

  const int as = t & 15, arw = t >> 4;   // A: 16 lanes x 16B = 256B per row
  const int bs = t & 7,  brw = t >> 3;   // B: 8 lanes x 16B = 128B per row

  auto LOADA = [&](int kt) {   // 8x coalesced global_load_dwordx4 -> regs
    const float* p = ((kt < 8) ? hT : xT)
                   + (size_t)(row0 + arw) * 512 + (kt & 7) * 64 + as * 4;
#pragma unroll
    for (int q = 0; q < 8; ++q) areg[q] = *(const f4*)(p + (size_t)q * 16 * 512);
  };
  auto LOADB = [&](int kt) {   // 4x linear global_load_dwordx4 (1KB/wave-instr)
    const _Float16* p = Bws + (size_t)kt * 32768 + (nt * 128 + brw) * 64 + bs * 8;
#pragma unroll
    for (int q = 0; q < 4; ++q) breg[q] = *(const uint4*)(p + q * 32 * 64);
  };
  auto WRITE = [&]() {         // cvt fp16 + swizzled LDS writes (conflict-free)
#pragma unroll
    for (int q = 0; q < 8; ++q) {       // A: 8x ds_write_b64
      const int R = arw + q * 16;
      const f4 v = areg[q];
      _Float16 hv[4];
      hv[0]=(_Float16)v[0]; hv[1]=(_Float16)v[1]; hv[2]=(_Float16)v[2]; hv[3]=(_Float16)v[3];
      *(uint2*)&Asm[R * 64 + (((as >> 1) ^ (R & 7)) << 3) + ((as & 1) << 2)] = *(uint2*)hv;
    }
#pragma unroll
    for (int q = 0; q < 4; ++q) {       // B: 4x ds_write_b128
      const int N = brw + q * 32;
      *(uint4*)&Bsm[N * 64 + ((bs ^ (N & 7)) << 3)] = breg[q];
    }
  };

  f32x16 acc[2][2];
#pragma unroll
  for (int mi = 0; mi < 2; ++mi)
#pragma unroll
    for (int ni = 0; ni < 2; ++ni)
      acc[mi][ni] = (f32x16)(0.f);

  // Prologue
  LOADA(0); LOADB(0);
  WRITE();             // waits tile0 loads (compiler-precise vmcnt)
  LOADA(1); LOADB(1);  // tile1 in flight across barrier (registers)
  LBAR();

#pragma unroll
  for (int kt = 0; kt < 16; ++kt) {
    // Compute tile kt from LDS: 4 ksteps x (2 A-reads + 2 B-reads + 4 MFMA)
#pragma unroll
    for (int ks = 0; ks < 4; ++ks) {
      h8 af[2], bf[2];
      const int sl = ks * 2 + khalf;
#pragma unroll
      for (int mi = 0; mi < 2; ++mi) {
        const int R = wm * 64 + mi * 32 + l31;
        af[mi] = *(const h8*)&Asm[R * 64 + ((sl ^ (R & 7)) << 3)];
      }
#pragma unroll
      for (int ni = 0; ni < 2; ++ni) {
        const int R = wn * 64 + ni * 32 + l31;
        bf[ni] = *(const h8*)&Bsm[R * 64 + ((sl ^ (R & 7)) << 3)];
      }
#pragma unroll
      for (int mi = 0; mi < 2; ++mi)
#pragma unroll
        for (int ni = 0; ni < 2; ++ni)
          acc[mi][ni] = __builtin_amdgcn_mfma_f32_32x32x16_f16(af[mi], bf[ni], acc[mi][ni], 0, 0, 0);
    }
    LBAR();                                   // all reads retired -> safe to overwrite
    if (kt < 15) {
      WRITE();                                // tile kt+1 (loaded 1 iter ago)
      if (kt < 14) { LOADA(kt + 2); LOADB(kt + 2); }
      LBAR();                                 // writes visible; loads stay in flight
    }
  }

  // Epilogue: e[row] += sum over this wave's 64 cols of tanh(u)*Ve.
  // 32x32 C layout: col = l&31, row = (reg&3) + 8*(reg>>2) + 4*khalf.
  float vev[2], biasv[2];
#pragma unroll
  for (int ni = 0; ni < 2; ++ni) {
    const int c = nt * 128 + wn * 64 + ni * 32 + l31;
    vev[ni]   = Ve[c];
    biasv[ni] = bias[(size_t)bb * 512 + c];
  }
#pragma unroll
  for (int mi = 0; mi < 2; ++mi) {
    float s[16];
#pragma unroll
    for (int r = 0; r < 16; ++r) {
      s[r] = tanhf(acc[mi][0][r] + biasv[0]) * vev[0]
           + tanhf(acc[mi][1][r] + biasv[1]) * vev[1];
#pragma unroll
      for (int d = 1; d < 32; d <<= 1) s[r] += __shfl_xor(s[r], d, 64);
    }
    if (l31 == 0) {
      const int rbase = row0 + wm * 64 + mi * 32 + 4 * khalf;
#pragma unroll
      for (int r = 0; r < 16; ++r)
        atomicAdd(&e[rbase + (r & 3) + 8 * (r >> 2)], s[r]);
    }
  }
}

// ---------------------------------------------------------------------------
// Softmax over S (in place: e -> alpha). One block per batch.
// ---------------------------------------------------------------------------
__global__ void softmax_kernel(float* __restrict__ e) {
  const int b = blockIdx.x, t = threadIdx.x;   // 256 threads
  float* row = e + (size_t)b * 512;
  float v0 = row[t], v1 = row[t + 256];
  float m = fmaxf(v0, v1);
#pragma unroll
  for (int d = 1; d < 64; d <<= 1) m = fmaxf(m, __shfl_xor(m, d, 64));
  __shared__ float r1[4], r2[4];
  if ((t & 63) == 0) r1[t >> 6] = m;
  __syncthreads();
  m = fmaxf(fmaxf(r1[0], r1[1]), fmaxf(r1[2], r1[3]));
  float e0 = expf(v0 - m), e1 = expf(v1 - m);
  float s = e0 + e1;
#pragma unroll
  for (int d = 1; d < 64; d <<= 1) s += __shfl_xor(s, d, 64);
  if ((t & 63) == 0) r2[t >> 6] = s;
  __syncthreads();
  s = r2[0] + r2[1] + r2[2] + r2[3];
  float inv = 1.0f / s;
  row[t]       = e0 * inv;
  row[t + 256] = e1 * inv;
}

// ---------------------------------------------------------------------------
// context[b][hd] = sum_s alpha[b][s] * h[b][s][hd]  (s split 4-way, atomic)
// ---------------------------------------------------------------------------
__global__ __launch_bounds__(512)
void ctx_kernel(const float* __restrict__ hT, const float* __restrict__ alpha,
                float* __restrict__ out) {
  const int b  = blockIdx.x >> 2;
  const int sc = blockIdx.x & 3;
  const int hd = threadIdx.x;
  __shared__ float al[128];
  if (threadIdx.x < 128) al[threadIdx.x] = alpha[(size_t)b * 512 + sc * 128 + threadIdx.x];
  __syncthreads();
  const float* hp = hT + ((size_t)b * 512 + sc * 128) * 512 + hd;
  float acc = 0.f;
#pragma unroll 4
  for (int s = 0; s < 128; ++s) acc += al[s] * hp[(size_t)s * 512];
  atomicAdd(&out[b * 512 + hd], acc);
}

// ---------------------------------------------------------------------------
extern "C" void kernel_launch(void* const* d_in, const int* in_sizes, int n_in,
                              void* d_out, int out_size, void* d_ws, size_t ws_size,
                              hipStream_t stream) {
  const float* h  = (const float*)d_in[0];
  const float* x  = (const float*)d_in[1];
  const float* Ve = (const float*)d_in[2];
  const float* U1 = (const float*)d_in[3];
  const float* U2 = (const float*)d_in[4];
  float* out = (float*)d_out;

  // ws layout: Bws fp16 kt-blocked 1 MB | bias f32 256 KB | e f32 256 KB
  _Float16* Bws  = (_Float16*)d_ws;
  float*    bias = (float*)((char*)d_ws + (1u << 20));
  float*    e    = (float*)((char*)d_ws + (1u << 20) + (256u << 10));
  if (ws_size < ((1u << 20) + (512u << 10))) return;

  hipMemsetAsync(e, 0, 65536 * sizeof(float), stream);
  hipMemsetAsync(d_out, 0, 65536 * sizeof(float), stream);

  bsetup_kernel<<<256, 256, 0, stream>>>(U1, U2, Bws);
  bias_kernel<<<128, 256, 0, stream>>>(h, U1, bias);
  gemm_kernel<<<2048, 256, 0, stream>>>(h, x, Bws, bias, Ve, e);
  softmax_kernel<<<128, 256, 0, stream>>>(e);
  ctx_kernel<<<512, 512, 0, stream>>>(h, e, out);
}

// Round 6
// 269.131 us; speedup vs baseline: 1.3203x; 1.3203x over previous
//
#include <hip/hip_runtime.h>
#include <cstdint>
#include <cstddef>

// Problem: B=128, S=512, H=512
//   context[b,h] = sum_s softmax_s( sum_k tanh(u[b,s,k]) Ve[k] ) * h[b,s,h]
//   u = h@U1a^T + x@U2^T + (h_last@U1b^T broadcast over s)
// R6: pre-convert h,x -> fp16; GEMM is m97-exact: global_load_lds staging for
//   A (chunk-XOR pre-swizzled source) and B (fragment-ordered image), single
//   32KB LDS buffer, 2 syncthreads/iter, zero loop VALU, 16x16x32 f16 MFMA.
//   Fallback to proven R2 path if ws too small for the fp16 copies.

typedef _Float16 h8 __attribute__((ext_vector_type(8)));
typedef float    f4 __attribute__((ext_vector_type(4)));

#define GLOAD16(g, l)                                                          \
  __builtin_amdgcn_global_load_lds(                                            \
      (const __attribute__((address_space(1))) void*)(g),                      \
      (__attribute__((address_space(3))) void*)(l), 16, 0, 0)

// ---------------------------------------------------------------------------
// Streaming f32 -> fp16 (row-major preserved). 8 elems / thread / iter.
// ---------------------------------------------------------------------------
__global__ __launch_bounds__(256)
void cvt_kernel(const float* __restrict__ src, _Float16* __restrict__ dst, int n8) {
  const int stride = gridDim.x * 256;
  for (int i = blockIdx.x * 256 + threadIdx.x; i < n8; i += stride) {
    const float* p = src + (size_t)i * 8;
    f4 a = *(const f4*)p, b = *(const f4*)(p + 4);
    _Float16 hv[8];
    hv[0]=(_Float16)a[0]; hv[1]=(_Float16)a[1]; hv[2]=(_Float16)a[2]; hv[3]=(_Float16)a[3];
    hv[4]=(_Float16)b[0]; hv[5]=(_Float16)b[1]; hv[6]=(_Float16)b[2]; hv[7]=(_Float16)b[3];
    *(uint4*)(dst + (size_t)i * 8) = *(uint4*)hv;
  }
}

// ---------------------------------------------------------------------------
// B image, FRAGMENT-ORDERED: chunk index g = [nt(4)][kt(16)][s(8)][grp(8)][l15(16)]
// chunk (16B = 8 fp16) = U[nt*128 + grp*16 + l15][kt*64 + s*8 .. +8]
// where U[n][k] = k<512 ? U1[n][k] : U2[n][k-512].
// A wave's ds_read_b128 for fragment (wn,nf,kk,lhi) is then lane-contiguous.
// ---------------------------------------------------------------------------
__global__ void bsetup2_kernel(const float* __restrict__ U1, const float* __restrict__ U2,
                               _Float16* __restrict__ Bimg) {
  int g = blockIdx.x * 256 + threadIdx.x;   // 65536 chunks
  int l15 = g & 15;
  int grp = (g >> 4) & 7;
  int s   = (g >> 7) & 7;
  int kt  = (g >> 10) & 15;
  int nt  = g >> 14;
  int n = nt * 128 + grp * 16 + l15;
  int k = kt * 64 + s * 8;
  const float* p = (k < 512) ? (U1 + (size_t)n * 1024 + k)
                             : (U2 + (size_t)n * 512 + (k - 512));
  f4 a = *(const f4*)p, b = *(const f4*)(p + 4);
  _Float16 hv[8];
  hv[0]=(_Float16)a[0]; hv[1]=(_Float16)a[1]; hv[2]=(_Float16)a[2]; hv[3]=(_Float16)a[3];
  hv[4]=(_Float16)b[0]; hv[5]=(_Float16)b[1]; hv[6]=(_Float16)b[2]; hv[7]=(_Float16)b[3];
  *(uint4*)(Bimg + (size_t)g * 8) = *(uint4*)hv;
}

// ---------------------------------------------------------------------------
// bias[b][n] = sum_h h[b][S-1][h] * U1[n][512+h]   (fp32, exact)
// ---------------------------------------------------------------------------
__global__ void bias_kernel(const float* __restrict__ hT, const float* __restrict__ U1,
                            float* __restrict__ bias) {
  const int b = blockIdx.x, t = threadIdx.x;
  const int l = t & 63, w = t >> 6;
  __shared__ float4 hl[128];
  if (t < 128) hl[t] = *(const float4*)(hT + ((size_t)b * 512 + 511) * 512 + t * 4);
  __syncthreads();
  for (int n = w; n < 512; n += 4) {
    const float4* ur = (const float4*)(U1 + (size_t)n * 1024 + 512);
    float4 u0 = ur[l],      u1 = ur[l + 64];
    float4 h0 = hl[l],      h1 = hl[l + 64];
    float s = u0.x*h0.x + u0.y*h0.y + u0.z*h0.z + u0.w*h0.w
            + u1.x*h1.x + u1.y*h1.y + u1.z*h1.z + u1.w*h1.w;
#pragma unroll
    for (int d = 1; d < 64; d <<= 1) s += __shfl_xor(s, d, 64);
    if (l == 0) bias[(size_t)b * 512 + n] = s;
  }
}

// ---------------------------------------------------------------------------
// Fused GEMM, all-fp16 staging via global_load_lds. M=65536, N=512, K=1024.
// BM=128 BN=128 BK=64. 4 waves (2x2), wave tile 64x64, 4x4 frags 16x16x32.
// A: LDS[row][chunk] holds A[row][(chunk^(row&7))*8..+8]  (XOR baked in DMA src,
//    XOR'd read base precomputed -> conflict-free, zero loop VALU).
// B: fragment-ordered image, DMA linear, reads lane-contiguous (conflict-free).
// ---------------------------------------------------------------------------
__global__ __launch_bounds__(256, 3)
void gemm2_kernel(const _Float16* __restrict__ hF, const _Float16* __restrict__ xF,
                  const _Float16* __restrict__ Bimg, const float* __restrict__ bias,
                  const float* __restrict__ Ve, float* __restrict__ e) {
  // XCD-chunked bijective swizzle (2048 = 8*256): nt-siblings adjacent on one XCD.
  const int bid  = ((int)blockIdx.x & 7) * 256 + ((int)blockIdx.x >> 3);
  const int bm   = bid >> 2;
  const int nt   = bid & 3;
  const int row0 = bm * 128;
  const int bb   = row0 >> 9;
  const int t    = threadIdx.x;
  const int l    = t & 63;
  const int wv   = t >> 6;
  const int wm   = wv >> 1, wn = wv & 1;
  const int l15  = l & 15, lhi = l >> 4;

  __shared__ __align__(16) _Float16 Asm[8192];   // 16 KB
  __shared__ __align__(16) _Float16 Bsm[8192];   // 16 KB

  // A DMA: instr j covers LDS rows wv*32+j*8 .. +8 (linear dest).
  // Per-lane source offset (fp16 elems), XOR pre-swizzle baked in:
  const int aoff0 = (wv * 32 + (l >> 3)) * 512 + (((l & 7) ^ (l >> 3)) << 3);

  auto STAGE = [&](int kt) {
    const _Float16* ah = ((kt < 8) ? hF : xF) + (size_t)row0 * 512 + (kt & 7) * 64;
#pragma unroll
    for (int j = 0; j < 4; ++j)
      GLOAD16(ah + aoff0 + j * 4096, &Asm[wv * 2048 + j * 512]);
    const _Float16* bt = Bimg + ((size_t)(nt * 16 + kt) << 13);
#pragma unroll
    for (int j = 0; j < 4; ++j)
      GLOAD16(bt + wv * 2048 + j * 512 + l * 8, &Bsm[wv * 2048 + j * 512]);
  };

  // Read bases (fp16-elem units), computed once:
  // A elem addr = wm*4096 + mf*1024 + l15*64 + ((kk*4+lhi)^(l15&7))*8
  const int vA0 = wm * 4096 + l15 * 64 + (((0 + lhi) ^ (l15 & 7)) << 3);
  const int vA1 = wm * 4096 + l15 * 64 + (((4 + lhi) ^ (l15 & 7)) << 3);
  // B elem addr = kk*4096 + lhi*1024 + (wn*4+nf)*128 + l15*8
  const int vB  = lhi * 1024 + wn * 512 + l15 * 8;

  f4 acc[4][4];
#pragma unroll
  for (int mf = 0; mf < 4; ++mf)
#pragma unroll
    for (int nf = 0; nf < 4; ++nf)
      acc[mf][nf] = (f4){0.f, 0.f, 0.f, 0.f};

  STAGE(0);

  for (int kt = 0; kt < 16; ++kt) {
    __syncthreads();                      // drains DMA, publishes tile kt
#pragma unroll
    for (int kk = 0; kk < 2; ++kk) {
      h8 af[4], bf[4];
      const int a0 = (kk ? vA1 : vA0);
#pragma unroll
      for (int mf = 0; mf < 4; ++mf)
        af[mf] = *(const h8*)&Asm[a0 + mf * 1024];
#pragma unroll
      for (int nf = 0; nf < 4; ++nf)
        bf[nf] = *(const h8*)&Bsm[vB + kk * 4096 + nf * 128];
#pragma unroll
      for (int mf = 0; mf < 4; ++mf)
#pragma unroll
        for (int nf = 0; nf < 4; ++nf)
          acc[mf][nf] = __builtin_amdgcn_mfma_f32_16x16x32_f16(af[mf], bf[nf], acc[mf][nf], 0, 0, 0);
    }
    __syncthreads();                      // reads done -> safe to overwrite
    if (kt < 15) STAGE(kt + 1);
  }

  // Epilogue: e[row] += sum over this wave's 64 cols of tanh(u)*Ve
  float vev[4], biasv[4];
#pragma unroll
  for (int nf = 0; nf < 4; ++nf) {
    int c = nt * 128 + wn * 64 + nf * 16 + l15;
    vev[nf]   = Ve[c];
    biasv[nf] = bias[(size_t)bb * 512 + c];
  }
#pragma unroll
  for (int mf = 0; mf < 4; ++mf) {
#pragma unroll
    for (int j = 0; j < 4; ++j) {
      float s = 0.f;
#pragma unroll
      for (int nf = 0; nf < 4; ++nf)
        s += tanhf(acc[mf][nf][j] + biasv[nf]) * vev[nf];
#pragma unroll
      for (int m = 1; m < 16; m <<= 1) s += __shfl_xor(s, m, 64);
      if (l15 == 0) atomicAdd(&e[row0 + wm * 64 + mf * 16 + lhi * 4 + j], s);
    }
  }
}

// ---------------------------------------------------------------------------
// Softmax over S (in place: e -> alpha). One block per batch.
// ---------------------------------------------------------------------------
__global__ void softmax_kernel(float* __restrict__ e) {
  const int b = blockIdx.x, t = threadIdx.x;   // 256 threads
  float* row = e + (size_t)b * 512;
  float v0 = row[t], v1 = row[t + 256];
  float m = fmaxf(v0, v1);
#pragma unroll
  for (int d = 1; d < 64; d <<= 1) m = fmaxf(m, __shfl_xor(m, d, 64));
  __shared__ float r1[4], r2[4];
  if ((t & 63) == 0) r1[t >> 6] = m;
  __syncthreads();
  m = fmaxf(fmaxf(r1[0], r1[1]), fmaxf(r1[2], r1[3]));
  float e0 = expf(v0 - m), e1 = expf(v1 - m);
  float s = e0 + e1;
#pragma unroll
  for (int d = 1; d < 64; d <<= 1) s += __shfl_xor(s, d, 64);
  if ((t & 63) == 0) r2[t >> 6] = s;
  __syncthreads();
  s = r2[0] + r2[1] + r2[2] + r2[3];
  float inv = 1.0f / s;
  row[t]       = e0 * inv;
  row[t + 256] = e1 * inv;
}

// ---------------------------------------------------------------------------
// context from fp16 h copy: out[b][hd] = sum_s alpha[b][s] * hF[b*512+s][hd]
// ---------------------------------------------------------------------------
__global__ __launch_bounds__(512)
void ctx16_kernel(const _Float16* __restrict__ hF, const float* __restrict__ alpha,
                  float* __restrict__ out) {
  const int b  = blockIdx.x >> 2;
  const int sc = blockIdx.x & 3;
  const int hd = threadIdx.x;
  __shared__ float al[128];
  if (threadIdx.x < 128) al[threadIdx.x] = alpha[(size_t)b * 512 + sc * 128 + threadIdx.x];
  __syncthreads();
  const _Float16* hp = hF + ((size_t)b * 512 + sc * 128) * 512 + hd;
  float acc = 0.f;
#pragma unroll 4
  for (int s = 0; s < 128; ++s) acc += al[s] * (float)hp[(size_t)s * 512];
  atomicAdd(&out[b * 512 + hd], acc);
}

// ===========================================================================
// FALLBACK path (ws too small for fp16 copies): proven R2 kernels verbatim.
// ===========================================================================
__global__ void bsetup_fb(const float* __restrict__ U1, const float* __restrict__ U2,
                          _Float16* __restrict__ Bws) {
  int g = blockIdx.x * 256 + threadIdx.x;
  int s  = g & 7;
  int r  = (g >> 3) & 255;
  int kt = (g >> 11) & 15;
  int nt = g >> 15;
  int n = nt * 256 + r;
  int k = kt * 64 + ((s ^ (r & 7)) << 3);
  const float* p = (k < 512) ? (U1 + (size_t)n * 1024 + k)
                             : (U2 + (size_t)n * 512 + (k - 512));
  float4 a = *(const float4*)p;
  float4 b = *(const float4*)(p + 4);
  _Float16 hv[8];
  hv[0]=(_Float16)a.x; hv[1]=(_Float16)a.y; hv[2]=(_Float16)a.z; hv[3]=(_Float16)a.w;
  hv[4]=(_Float16)b.x; hv[5]=(_Float16)b.y; hv[6]=(_Float16)b.z; hv[7]=(_Float16)b.w;
  *(uint4*)(Bws + ((size_t)((nt * 16 + kt) * 256 + r) << 6) + (s << 3)) = *(uint4*)hv;
}

__global__ __launch_bounds__(256, 3)
void gemm_fb(const float* __restrict__ hT, const float* __restrict__ xT,
             const _Float16* __restrict__ Bws, const float* __restrict__ bias,
             const float* __restrict__ Ve, float* __restrict__ e) {
  const int bid  = ((int)blockIdx.x & 7) * 256 + ((int)blockIdx.x >> 3);
  const int bm   = bid >> 1;
  const int nt   = bid & 1;
  const int row0 = bm * 64;
  const int bb   = row0 >> 9;
  const int t    = threadIdx.x;
  const int l    = t & 63;
  const int wv   = t >> 6;
  const int l15  = l & 15;
  const int lhi  = l >> 4;

  __shared__ __align__(16) float    Asm[64 * 64];
  __shared__ __align__(16) _Float16 Bsm[256 * 64];

  auto STAGE = [&](int kt) {
    const float* srcA = (kt < 8) ? hT : xT;
    const int kc = (kt & 7) * 64;
#pragma unroll
    for (int j = 0; j < 4; ++j) {
      int r = wv * 16 + j * 4 + (l >> 4);
      int s = l & 15;
      const float* g = srcA + (size_t)(row0 + r) * 512 + kc + ((s ^ (r & 7)) << 2);
      GLOAD16(g, &Asm[(wv * 16 + j * 4) * 64]);
    }
    const _Float16* tb = Bws + ((size_t)(nt * 16 + kt) << 14);
#pragma unroll
    for (int j = 0; j < 8; ++j) {
      const _Float16* g = tb + (wv * 8 + j) * 512 + l * 8;
      GLOAD16(g, &Bsm[(wv * 8 + j) * 512]);
    }
  };

  f4 acc[4][4];
#pragma unroll
  for (int mf = 0; mf < 4; ++mf)
#pragma unroll
    for (int nf = 0; nf < 4; ++nf)
      acc[mf][nf] = (f4){0.f, 0.f, 0.f, 0.f};

  STAGE(0);

  for (int kt = 0; kt < 16; ++kt) {
    __syncthreads();
#pragma unroll
    for (int kk = 0; kk < 2; ++kk) {
      h8 af[4], bf[4];
#pragma unroll
      for (int mf = 0; mf < 4; ++mf) {
        int rA = mf * 16 + l15;
        int c0 = kk * 8 + lhi * 2;
        const float4 a0 = *(const float4*)&Asm[rA * 64 + ((c0 ^ (rA & 7)) << 2)];
        const float4 a1 = *(const float4*)&Asm[rA * 64 + (((c0 + 1) ^ (rA & 7)) << 2)];
        h8 tf;
        tf[0]=(_Float16)a0.x; tf[1]=(_Float16)a0.y; tf[2]=(_Float16)a0.z; tf[3]=(_Float16)a0.w;
        tf[4]=(_Float16)a1.x; tf[5]=(_Float16)a1.y; tf[6]=(_Float16)a1.z; tf[7]=(_Float16)a1.w;
        af[mf] = tf;
      }
#pragma unroll
      for (int nf = 0; nf < 4; ++nf) {
        int rB = wv * 64 + nf * 16 + l15;
        bf[nf] = *(const h8*)&Bsm[rB * 64 + ((((kk << 2) + lhi) ^ (rB & 7)) << 3)];
      }
#pragma unroll
      for (int mf = 0; mf < 4; ++mf)
#pragma unroll
        for (int nf = 0; nf < 4; ++nf)
          acc[mf][nf] = __builtin_amdgcn_mfma_f32_16x16x32_f16(af[mf], bf[nf], acc[mf][nf], 0, 0, 0);
    }
    __syncthreads();
    if (kt < 15) STAGE(kt + 1);
  }

  float vev[4], biasv[4];
#pragma unroll
  for (int nf = 0; nf < 4; ++nf) {
    int c = nt * 256 + wv * 64 + nf * 16 + l15;
    vev[nf]   = Ve[c];
    biasv[nf] = bias[(size_t)bb * 512 + c];
  }
#pragma unroll
  for (int mf = 0; mf < 4; ++mf) {
#pragma unroll
    for (int j = 0; j < 4; ++j) {
      float s = 0.f;
#pragma unroll
      for (int nf = 0; nf < 4; ++nf)
        s += tanhf(acc[mf][nf][j] + biasv[nf]) * vev[nf];
#pragma unroll
      for (int m = 1; m < 16; m <<= 1) s += __shfl_xor(s, m, 64);
      if (l15 == 0) atomicAdd(&e[row0 + mf * 16 + lhi * 4 + j], s);
    }
  }
}

__global__ __launch_bounds__(512)
void ctx_fb(const float* __restrict__ hT, const float* __restrict__ alpha,
            float* __restrict__ out) {
  const int b  = blockIdx.x >> 2;
  const int sc = blockIdx.x & 3;
  const int hd = threadIdx.x;
  __shared__ float al[128];
  if (threadIdx.x < 128) al[threadIdx.x] = alpha[(size_t)b * 512 + sc * 128 + threadIdx.x];
  __syncthreads();
  const float* hp = hT + ((size_t)b * 512 + sc * 128) * 512 + hd;
  float acc = 0.f;
#pragma unroll 4
  for (int s = 0; s < 128; ++s) acc += al[s] * hp[(size_t)s * 512];
  atomicAdd(&out[b * 512 + hd], acc);
}

// ---------------------------------------------------------------------------
extern "C" void kernel_launch(void* const* d_in, const int* in_sizes, int n_in,
                              void* d_out, int out_size, void* d_ws, size_t ws_size,
                              hipStream_t stream) {
  const float* h  = (const float*)d_in[0];
  const float* x  = (const float*)d_in[1];
  const float* Ve = (const float*)d_in[2];
  const float* U1 = (const float*)d_in[3];
  const float* U2 = (const float*)d_in[4];
  float* out = (float*)d_out;

  const size_t MB = 1u << 20;

  if (ws_size >= 130 * MB) {
    // ws: hF 64MB | xF 64MB | Bimg 1MB | bias 256KB | e 256KB
    _Float16* hF   = (_Float16*)d_ws;
    _Float16* xF   = (_Float16*)((char*)d_ws + 64 * MB);
    _Float16* Bimg = (_Float16*)((char*)d_ws + 128 * MB);
    float*    bias = (float*)((char*)d_ws + 129 * MB);
    float*    e    = (float*)((char*)d_ws + 129 * MB + 256 * 1024);

    hipMemsetAsync(e, 0, 65536 * sizeof(float), stream);
    hipMemsetAsync(d_out, 0, 65536 * sizeof(float), stream);

    cvt_kernel<<<4096, 256, 0, stream>>>(h, hF, 4194304);
    cvt_kernel<<<4096, 256, 0, stream>>>(x, xF, 4194304);
    bsetup2_kernel<<<256, 256, 0, stream>>>(U1, U2, Bimg);
    bias_kernel<<<128, 256, 0, stream>>>(h, U1, bias);
    gemm2_kernel<<<2048, 256, 0, stream>>>(hF, xF, Bimg, bias, Ve, e);
    softmax_kernel<<<128, 256, 0, stream>>>(e);
    ctx16_kernel<<<512, 512, 0, stream>>>(hF, e, out);
  } else {
    if (ws_size < ((1u << 20) + (512u << 10))) return;
    _Float16* Bws  = (_Float16*)d_ws;
    float*    bias = (float*)((char*)d_ws + MB);
    float*    e    = (float*)((char*)d_ws + MB + 256 * 1024);

    hipMemsetAsync(e, 0, 65536 * sizeof(float), stream);
    hipMemsetAsync(d_out, 0, 65536 * sizeof(float), stream);

    bsetup_fb<<<256, 256, 0, stream>>>(U1, U2, Bws);
    bias_kernel<<<128, 256, 0, stream>>>(h, U1, bias);
    gemm_fb<<<2048, 256, 0, stream>>>(h, x, Bws, bias, Ve, e);
    softmax_kernel<<<128, 256, 0, stream>>>(e);
    ctx_fb<<<512, 512, 0, stream>>>(h, e, out);
  }
}